// Round 15
// baseline (25.041 us; speedup 1.0000x reference)
//
#include <hip/hip_runtime.h>
#include <hip/hip_fp16.h>
#include <math.h>

// T=24, NSEQ=16384, FS=64, FM=16, FC=16 -> I=96; H=32.
//
// R15 = R14 + K=2 double-step intervals (12 barrier rounds instead of 24).
//  - block = 128 thr: wave0 = CONSUMER (all 32 units, in-register sigma
//    recurrence), wave1 = PRODUCER (xacc tiles for TWO steps per interval
//    into double-buffered LDS).
//  - Consumer interval: barrier -> issue 12 ds_read_b128 (both steps) ->
//    step A -> step B (B's LDS latency hidden under A's compute).
//  - Producer interval: 2 packs + 12 MFMAs + 12 ds_writes + 4 global loads
//    (2-interval = 4-step prefetch distance).
//  - LDS 30 KB -> 4 blocks/CU; 1024 blocks = 2048 waves = 2/SIMD.
//  - Weights gathered directly (R12-validated), RN-pack, log2e-scaled;
//    merged-rcp gates (5 trans/unit, algebraic minimum).

typedef __attribute__((ext_vector_type(8))) _Float16 half8;
typedef __attribute__((ext_vector_type(4))) float f32x4;
typedef __attribute__((ext_vector_type(4))) unsigned int uix4;

#define NSEQ 16384
#define TSTEPS 24
#define NINT 12
#define LOG2E 1.44269504088896340736f

__device__ __forceinline__ float exp2_fast(float x) {
#if __has_builtin(__builtin_amdgcn_exp2f)
  return __builtin_amdgcn_exp2f(x);
#else
  return __expf(x * 0.6931471805599453f);
#endif
}

// runtime pack (RTZ) — data
__device__ __forceinline__ unsigned int pk_f16(float a, float b) {
#if __has_builtin(__builtin_amdgcn_cvt_pkrtz)
  auto r = __builtin_amdgcn_cvt_pkrtz(a, b);
  return __builtin_bit_cast(unsigned int, r);
#else
  return (unsigned)__half_as_ushort(__float2half(a)) |
         ((unsigned)__half_as_ushort(__float2half(b)) << 16);
#endif
}
// prologue pack (RN) — weights
__device__ __forceinline__ unsigned int pk_f16_rn(float a, float b) {
  return (unsigned)__half_as_ushort(__float2half(a)) |
         ((unsigned)__half_as_ushort(__float2half(b)) << 16);
}
__device__ __forceinline__ half8 mk_h8(unsigned int a, unsigned int b,
                                       unsigned int c, unsigned int d) {
  uix4 v = {a, b, c, d};
  return __builtin_bit_cast(half8, v);
}
__device__ __forceinline__ f32x4 mfma_h(half8 a, half8 b, f32x4 c) {
  return __builtin_amdgcn_mfma_f32_16x16x32_f16(a, b, c, 0, 0, 0);
}

// workgroup barrier draining LDS ops only
__device__ __forceinline__ void barrier_lds() {
  asm volatile("s_waitcnt lgkmcnt(0)" ::: "memory");
  __builtin_amdgcn_s_barrier();
}

__global__ __launch_bounds__(128, 4)
void gru11(const float* __restrict__ spatial,
           const float* __restrict__ met,
           const float* __restrict__ ctx,
           const float* __restrict__ W_ih,
           const float* __restrict__ W_hh,
           const float* __restrict__ b_ih,
           const float* __restrict__ b_hh,
           const float* __restrict__ Wp,
           float* __restrict__ out) {
  // xacc tiles: [buf][step-in-interval][tile j][seq 16][20-pad f32] = 30 KB
  __shared__ float xls[2][2][6][16][20];

  const int tid = threadIdx.x;
  const int lane = tid & 63;
  const int wv = tid >> 6;         // 0 = consumer, 1 = producer
  const int l15 = lane & 15;
  const int c = lane >> 4;         // 0..3
  const int seq = blockIdx.x * 16 + l15;
  const f32x4 zero4 = {0.f, 0.f, 0.f, 0.f};

  if (wv == 1) {
    // ======================= PRODUCER =======================
    half8 wmc[6];
    f32x4 acc_i[6];
#pragma unroll
    for (int j = 0; j < 6; ++j) {
      const float sc = (j < 4) ? LOG2E : (2.0f * LOG2E);
      const float* mr = W_ih + (size_t)(j * 16 + l15) * 96 + 64 + c * 8;
      float4 wa = *(const float4*)mr;
      float4 wb = *(const float4*)(mr + 4);
      wmc[j] = mk_h8(pk_f16_rn(wa.x * sc, wa.y * sc),
                     pk_f16_rn(wa.z * sc, wa.w * sc),
                     pk_f16_rn(wb.x * sc, wb.y * sc),
                     pk_f16_rn(wb.z * sc, wb.w * sc));
      const int rowb = j * 16 + 4 * c;
      float4 vih = *(const float4*)(b_ih + rowb);
      if (j < 4) {
        float4 vhh = *(const float4*)(b_hh + rowb);
        acc_i[j][0] = (vih.x + vhh.x) * sc; acc_i[j][1] = (vih.y + vhh.y) * sc;
        acc_i[j][2] = (vih.z + vhh.z) * sc; acc_i[j][3] = (vih.w + vhh.w) * sc;
      } else {
        acc_i[j][0] = vih.x * sc; acc_i[j][1] = vih.y * sc;
        acc_i[j][2] = vih.z * sc; acc_i[j][3] = vih.w * sc;
      }
    }
    // fold spatial (time-invariant)
#pragma unroll
    for (int kt = 0; kt < 2; ++kt) {
      const float* sp = spatial + (size_t)seq * 64 + kt * 32 + c * 8;
      float4 a0 = *(const float4*)sp;
      float4 a1 = *(const float4*)(sp + 4);
      half8 sf = mk_h8(pk_f16(a0.x, a0.y), pk_f16(a0.z, a0.w),
                       pk_f16(a1.x, a1.y), pk_f16(a1.z, a1.w));
#pragma unroll
      for (int j = 0; j < 6; ++j) {
        const float sc = (j < 4) ? LOG2E : (2.0f * LOG2E);
        const float* wr = W_ih + (size_t)(j * 16 + l15) * 96 + kt * 32 + c * 8;
        float4 wa = *(const float4*)wr;
        float4 wb = *(const float4*)(wr + 4);
        half8 wsp = mk_h8(pk_f16_rn(wa.x * sc, wa.y * sc),
                          pk_f16_rn(wa.z * sc, wa.w * sc),
                          pk_f16_rn(wb.x * sc, wb.y * sc),
                          pk_f16_rn(wb.z * sc, wb.w * sc));
        acc_i[j] = mfma_h(wsp, sf, acc_i[j]);
      }
    }
    const float* lptr = ((c < 2) ? met : ctx) + (size_t)seq * 16 + (c & 1) * 8;

    auto fill = [&](int buf, int s, float4 xa, float4 xb) {
      half8 xf = mk_h8(pk_f16(xa.x, xa.y), pk_f16(xa.z, xa.w),
                       pk_f16(xb.x, xb.y), pk_f16(xb.z, xb.w));
#pragma unroll
      for (int j = 0; j < 6; ++j) {
        f32x4 D = mfma_h(wmc[j], xf, acc_i[j]);
        *(f32x4*)&xls[buf][s][j][l15][c * 4] = D;
      }
    };
    auto ldx = [&](int t, float4& a, float4& b) {
      const float* p = lptr + (size_t)t * NSEQ * 16;
      a = *(const float4*)p; b = *(const float4*)(p + 4);
    };

    // prologue: buf0 <- steps 0,1; cur = x(2,3); next = x(4,5)
    {
      float4 a0, b0, a1, b1;
      ldx(0, a0, b0); ldx(1, a1, b1);
      fill(0, 0, a0, b0); fill(0, 1, a1, b1);
    }
    float4 c0a, c0b, c1a, c1b, n0a, n0b, n1a, n1b;
    ldx(2, c0a, c0b); ldx(3, c1a, c1b);
    ldx(4, n0a, n0b); ldx(5, n1a, n1b);

#pragma unroll 2
    for (int k = 0; k < NINT; ++k) {
      barrier_lds();                       // buf[k&1] ready for consumer
      if (k < NINT - 1) {
        fill((k + 1) & 1, 0, c0a, c0b);
        fill((k + 1) & 1, 1, c1a, c1b);
        c0a = n0a; c0b = n0b; c1a = n1a; c1b = n1b;
        int t0 = (2 * k + 6 < TSTEPS) ? (2 * k + 6) : (TSTEPS - 1);
        int t1 = (2 * k + 7 < TSTEPS) ? (2 * k + 7) : (TSTEPS - 1);
        ldx(t0, n0a, n0b); ldx(t1, n1a, n1b);
      }
    }
    // producer done
  } else {
    // ======================= CONSUMER =======================
    __builtin_amdgcn_s_setprio(1);
    half8 whh[6];
#pragma unroll
    for (int j = 0; j < 6; ++j) {
      const float sc = (j < 4) ? LOG2E : (2.0f * LOG2E);
      const float* wr = W_hh + (size_t)(j * 16 + l15) * 32;
      float4 a = *(const float4*)(wr + 4 * c);
      float4 b = *(const float4*)(wr + 16 + 4 * c);
      whh[j] = mk_h8(pk_f16_rn(a.x * sc, a.y * sc),
                     pk_f16_rn(a.z * sc, a.w * sc),
                     pk_f16_rn(b.x * sc, b.y * sc),
                     pk_f16_rn(b.z * sc, b.w * sc));
    }
    f32x4 bhnA, bhnB;
    {
      float4 va = *(const float4*)(b_hh + 64 + 4 * c);
      float4 vb = *(const float4*)(b_hh + 64 + 16 + 4 * c);
      bhnA[0] = 2.0f * LOG2E * va.x; bhnA[1] = 2.0f * LOG2E * va.y;
      bhnA[2] = 2.0f * LOG2E * va.z; bhnA[3] = 2.0f * LOG2E * va.w;
      bhnB[0] = 2.0f * LOG2E * vb.x; bhnB[1] = 2.0f * LOG2E * vb.y;
      bhnB[2] = 2.0f * LOG2E * vb.z; bhnB[3] = 2.0f * LOG2E * vb.w;
    }
    float hst[8];
#pragma unroll
    for (int i = 0; i < 8; ++i) hst[i] = 0.0f;
    half8 fh = mk_h8(0u, 0u, 0u, 0u);

    auto do_step = [&](f32x4 xr0, f32x4 xr1, f32x4 xz0, f32x4 xz1,
                       f32x4 ti0, f32x4 ti1) {
      f32x4 dr0 = mfma_h(whh[0], fh, xr0);
      f32x4 dr1 = mfma_h(whh[1], fh, xr1);
      f32x4 dz0 = mfma_h(whh[2], fh, xz0);
      f32x4 dz1 = mfma_h(whh[3], fh, xz1);
      f32x4 th0 = mfma_h(whh[4], fh, bhnA);
      f32x4 th1 = mfma_h(whh[5], fh, bhnB);
      float hv_[8];
#pragma unroll
      for (int jj = 0; jj < 2; ++jj) {
        f32x4 ddr = jj ? dr1 : dr0;
        f32x4 ddz = jj ? dz1 : dz0;
        f32x4 tth = jj ? th1 : th0;
        f32x4 tti = jj ? ti1 : ti0;
#pragma unroll
        for (int q = 0; q < 4; ++q) {
          const int i = jj * 4 + q;
          float R = exp2_fast(-ddr[q]);
          float r = __builtin_amdgcn_rcpf(1.0f + R);
          float E = fminf(exp2_fast(-ddz[q]), 1e30f);
          float Y = fmaf(r, tth[q], tti[q]);
          float e = fminf(exp2_fast(-Y), 1e30f);
          float oe = 1.0f + e, oE = 1.0f + E;
          float inv = __builtin_amdgcn_rcpf(oE * oe);
          float num = fmaf(hst[i], oe, fmaf(-E, e, E));
          float hv = num * inv;
          hst[i] = hv;
          hv_[i] = hv;
        }
      }
      fh = mk_h8(pk_f16(hv_[0], hv_[1]), pk_f16(hv_[2], hv_[3]),
                 pk_f16(hv_[4], hv_[5]), pk_f16(hv_[6], hv_[7]));
    };

#pragma unroll 2
    for (int k = 0; k < NINT; ++k) {
      const int buf = k & 1;
      barrier_lds();                       // buf ready (steps 2k, 2k+1)
      // issue ALL 12 ds_reads up front; step B latency hides under step A
      f32x4 A0 = *(const f32x4*)&xls[buf][0][0][l15][c * 4];
      f32x4 A1 = *(const f32x4*)&xls[buf][0][1][l15][c * 4];
      f32x4 A2 = *(const f32x4*)&xls[buf][0][2][l15][c * 4];
      f32x4 A3 = *(const f32x4*)&xls[buf][0][3][l15][c * 4];
      f32x4 A4 = *(const f32x4*)&xls[buf][0][4][l15][c * 4];
      f32x4 A5 = *(const f32x4*)&xls[buf][0][5][l15][c * 4];
      f32x4 B0 = *(const f32x4*)&xls[buf][1][0][l15][c * 4];
      f32x4 B1 = *(const f32x4*)&xls[buf][1][1][l15][c * 4];
      f32x4 B2 = *(const f32x4*)&xls[buf][1][2][l15][c * 4];
      f32x4 B3 = *(const f32x4*)&xls[buf][1][3][l15][c * 4];
      f32x4 B4 = *(const f32x4*)&xls[buf][1][4][l15][c * 4];
      f32x4 B5 = *(const f32x4*)&xls[buf][1][5][l15][c * 4];
      do_step(A0, A1, A2, A3, A4, A5);
      do_step(B0, B1, B2, B3, B4, B5);
    }

    // ---- projection: all 4 f-tiles; Wp gathered (sigma cols), f16 2-term ----
#pragma unroll
    for (int pt = 0; pt < 4; ++pt) {
      const int frow = pt * 16 + l15;
      const float* wpb = Wp + frow;
      float v[8];
#pragma unroll
      for (int e = 0; e < 8; ++e) {
        int col = (e < 4) ? (4 * c + e) : (16 + 4 * c + (e - 4));
        v[e] = wpb[(size_t)col * 64];
      }
      unsigned int uh[4], ul[4];
#pragma unroll
      for (int e2 = 0; e2 < 4; ++e2) {
        float va = v[2 * e2], vb = v[2 * e2 + 1];
        __half ha = __float2half(va), hb = __float2half(vb);
        float la = va - __half2float(ha), lb = vb - __half2float(hb);
        uh[e2] = (unsigned)__half_as_ushort(ha) |
                 ((unsigned)__half_as_ushort(hb) << 16);
        ul[e2] = pk_f16_rn(la, lb);
      }
      half8 wph = mk_h8(uh[0], uh[1], uh[2], uh[3]);
      half8 wpl = mk_h8(ul[0], ul[1], ul[2], ul[3]);
      f32x4 o = mfma_h(wph, fh, zero4);
      o = mfma_h(wpl, fh, o);
      float* op = out + (size_t)seq * 64 + pt * 16 + 4 * c;
      *(float4*)op = make_float4(o[0], o[1], o[2], o[3]);
    }
    __builtin_amdgcn_s_setprio(0);
  }
}

extern "C" void kernel_launch(void* const* d_in, const int* in_sizes, int n_in,
                              void* d_out, int out_size, void* d_ws, size_t ws_size,
                              hipStream_t stream) {
  const float* spatial = (const float*)d_in[0];
  const float* met     = (const float*)d_in[1];
  const float* ctx     = (const float*)d_in[2];
  const float* W_ih    = (const float*)d_in[3];
  const float* W_hh    = (const float*)d_in[4];
  const float* b_ih    = (const float*)d_in[5];
  const float* b_hh    = (const float*)d_in[6];
  const float* Wp      = (const float*)d_in[7];
  float* out = (float*)d_out;

  hipLaunchKernelGGL(gru11, dim3(1024), dim3(128), 0, stream,
                     spatial, met, ctx, W_ih, W_hh, b_ih, b_hh, Wp, out);
}